// Round 2
// baseline (3722.518 us; speedup 1.0000x reference)
//
#include <hip/hip_runtime.h>

#define MAX_ITER 8192
#define NCHUNK 64                       // iterations per chunk (one wave in Phase B)
#define NCHUNKS (MAX_ITER / NCHUNK)     // 128
#define NTHREADS 1024
#define GROUP 16                        // threads per sample in Phase A

// IEEE fp32 ops with contraction disabled -> bitwise-match numpy reference.
__device__ __forceinline__ float mul_rn(float a, float b) {
#pragma clang fp contract(off)
  return a * b;
}
__device__ __forceinline__ float add_rn(float a, float b) {
#pragma clang fp contract(off)
  return a + b;
}
__device__ __forceinline__ float sub_rn(float a, float b) {
#pragma clang fp contract(off)
  return a - b;
}

__device__ __forceinline__ float bcastf(float v, int lane) {
  return __int_as_float(__builtin_amdgcn_readlane(__float_as_int(v), lane));
}

__global__ __launch_bounds__(NTHREADS) void rrt_kernel(
    const float* __restrict__ state, const float* __restrict__ goal,
    const float* __restrict__ u, const float* __restrict__ r,
    float* __restrict__ out) {
  // LDS: nodes 1..8192 (node 0 kept in registers). Exactly 64 KiB.
  __shared__ float2 nodesL[MAX_ITER];   // nodesL[k] == node (k+1)

  const int tid = threadIdx.x;
  const float n0x = state[0];
  const float n0y = state[1];
  const float gx = goal[0], gy = goal[1];

  const int g = tid >> 4;     // sample group 0..63 (Phase A)
  const int sub = tid & 15;   // lane within group

  for (int chunk = 0; chunk < NCHUNKS; ++chunk) {
    const int c = chunk * NCHUNK;   // nodes 0..c exist; iterations c..c+63 run now

    // ---- my group's sample (recomputed redundantly; identical ops everywhere)
    float sx, sy;
    {
      const int i = c + g;
      const float uu = u[i];
      if (uu < 0.1f) {
        sx = gx; sy = gy;
      } else {
        sx = mul_rn(r[2 * i], 200.0f);      // lo + r*(hi-lo), lo=0, hi-lo=200
        sy = mul_rn(r[2 * i + 1], 200.0f);
      }
    }

    // ---- Phase A: argmin_{j in [0..c]} d2(sample, node_j), 16 lanes/sample
    {
      float bd2 = 3.0e38f;
      int bidx = 0;
      if (sub == 0) {  // node 0 from registers
        const float dx = sub_rn(n0x, sx);
        const float dy = sub_rn(n0y, sy);
        bd2 = add_rn(mul_rn(dx, dx), mul_rn(dy, dy));
        bidx = 0;
      }
      for (int j = (sub == 0 ? GROUP : sub); j <= c; j += GROUP) {
        const float2 p = nodesL[j - 1];
        const float dx = sub_rn(p.x, sx);
        const float dy = sub_rn(p.y, sy);
        const float d2 = add_rn(mul_rn(dx, dx), mul_rn(dy, dy));
        if (d2 < bd2) { bd2 = d2; bidx = j; }   // strict < keeps lowest index
      }
      // reduce across the 16-lane subgroup (xor 8,4,2,1 stays inside group)
      #pragma unroll
      for (int m = 8; m >= 1; m >>= 1) {
        const float od2 = __shfl_xor(bd2, m, 64);
        const int oidx = __shfl_xor(bidx, m, 64);
        if (od2 < bd2 || (od2 == bd2 && oidx < bidx)) { bd2 = od2; bidx = oidx; }
      }
      // stash partial in the not-yet-written node slot for iteration c+g
      if (sub == 0) {
        nodesL[c + g] = make_float2(bd2, __int_as_float(bidx));
      }
    }
    __syncthreads();

    // ---- Phase B: wave 0 runs the 64 sequential steps
    if (tid < 64) {
      const int lane = tid;

      // THIS lane owns iteration c+lane: recompute ITS sample (the Phase-A
      // registers hold sample c+(tid>>4) -- the round-1 bug).
      float sxx, syy;
      {
        const int i = c + lane;
        const float uu = u[i];
        if (uu < 0.1f) { sxx = gx; syy = gy; }
        else {
          sxx = mul_rn(r[2 * i], 200.0f);
          syy = mul_rn(r[2 * i + 1], 200.0f);
        }
      }

      const float2 part = nodesL[c + lane];
      float bd2 = part.x;
      const int bidx = __float_as_int(part.y);
      float bx, by;
      if (bidx == 0) { bx = n0x; by = n0y; }
      else { const float2 bp = nodesL[bidx - 1]; bx = bp.x; by = bp.y; }

      for (int t = 0; t < NCHUNK; ++t) {
        // lane t's final argmin state -> uniform values on all lanes
        const float td2 = bcastf(bd2, t);
        const float tx = bcastf(bx, t);
        const float ty = bcastf(by, t);
        const float tsx = bcastf(sxx, t);
        const float tsy = bcastf(syy, t);
        const float dirx = sub_rn(tsx, tx);
        const float diry = sub_rn(tsy, ty);
        const float dist = __fsqrt_rn(add_rn(td2, 1e-12f));
        const float scl = (dist > 5.0f) ? __fdiv_rn(5.0f, dist) : 1.0f;
        const float nx = add_rn(tx, mul_rn(dirx, scl));
        const float ny = add_rn(ty, mul_rn(diry, scl));
        if (lane == 0) nodesL[c + t] = make_float2(nx, ny);  // node c+t+1
        if (lane > t) {  // pending samples absorb the new node
          const float dx = sub_rn(nx, sxx);
          const float dy = sub_rn(ny, syy);
          const float nd2 = add_rn(mul_rn(dx, dx), mul_rn(dy, dy));
          if (nd2 < bd2) { bd2 = nd2; bx = nx; by = ny; }  // strict <: old idx wins ties
        }
      }
    }
    __syncthreads();
  }

  // ---- write out nodes[0..8192] as float pairs
  if (tid == 0) { out[0] = n0x; out[1] = n0y; }
  for (int i = 1 + tid; i <= MAX_ITER; i += NTHREADS) {
    const float2 p = nodesL[i - 1];
    out[2 * i] = p.x;
    out[2 * i + 1] = p.y;
  }
}

extern "C" void kernel_launch(void* const* d_in, const int* in_sizes, int n_in,
                              void* d_out, int out_size, void* d_ws, size_t ws_size,
                              hipStream_t stream) {
  const float* state = (const float*)d_in[0];
  const float* goal  = (const float*)d_in[1];
  const float* u     = (const float*)d_in[2];
  const float* r     = (const float*)d_in[3];
  float* out = (float*)d_out;
  (void)in_sizes; (void)n_in; (void)out_size; (void)d_ws; (void)ws_size;
  rrt_kernel<<<1, NTHREADS, 0, stream>>>(state, goal, u, r, out);
}

// Round 3
// 3091.591 us; speedup vs baseline: 1.2041x; 1.2041x over previous
//
#include <hip/hip_runtime.h>

#define MAX_ITER 8192
#define NCHUNK 64                       // iterations per chunk (one wave in Phase B)
#define NCHUNKS (MAX_ITER / NCHUNK)     // 128
#define NTHREADS 1024

// IEEE fp32 ops with contraction disabled -> bitwise-match numpy reference.
__device__ __forceinline__ float mul_rn(float a, float b) {
#pragma clang fp contract(off)
  return a * b;
}
__device__ __forceinline__ float add_rn(float a, float b) {
#pragma clang fp contract(off)
  return a + b;
}
__device__ __forceinline__ float sub_rn(float a, float b) {
#pragma clang fp contract(off)
  return a - b;
}

__device__ __forceinline__ float bcastf(float v, int lane) {
  return __int_as_float(__builtin_amdgcn_readlane(__float_as_int(v), lane));
}

__global__ __launch_bounds__(NTHREADS) void rrt_kernel(
    const float* __restrict__ state, const float* __restrict__ goal,
    const float* __restrict__ u, const float* __restrict__ r,
    float* __restrict__ out) {
  // LDS: nodes 1..8192 (node 0 kept in registers). Exactly 64 KiB.
  __shared__ float2 nodesL[MAX_ITER];   // nodesL[k] == node (k+1)

  const int tid = threadIdx.x;
  const int wave = tid >> 6;   // 0..15
  const int lane = tid & 63;
  const float n0x = state[0];
  const float n0y = state[1];
  const float gx = goal[0], gy = goal[1];

  for (int chunk = 0; chunk < NCHUNKS; ++chunk) {
    const int c = chunk * NCHUNK;   // nodes 0..c exist; iterations c..c+63 run now

    // ---- Phase A (wave-stationary samples): wave w owns samples c+4w..c+4w+3.
    // Lanes stride over nodes; one ds_read_b64 serves 4 samples.
    float sxv[4], syv[4];
    #pragma unroll
    for (int s = 0; s < 4; ++s) {
      const int i = c + wave * 4 + s;
      const float uu = u[i];
      if (uu < 0.1f) { sxv[s] = gx; syv[s] = gy; }
      else {
        sxv[s] = mul_rn(r[2 * i], 200.0f);      // lo + r*(hi-lo), lo=0, hi-lo=200
        syv[s] = mul_rn(r[2 * i + 1], 200.0f);
      }
    }

    float bd2v[4] = {3.0e38f, 3.0e38f, 3.0e38f, 3.0e38f};
    int bidxv[4] = {0, 0, 0, 0};

    for (int base = 0; base <= c; base += 64) {
      const int j = base + lane;
      if (j <= c) {
        const int jm = (j == 0) ? 0 : (j - 1);   // avoid nodesL[-1]
        const float2 p = nodesL[jm];
        const float px = (j == 0) ? n0x : p.x;
        const float py = (j == 0) ? n0y : p.y;
        #pragma unroll
        for (int s = 0; s < 4; ++s) {
          const float dx = sub_rn(px, sxv[s]);
          const float dy = sub_rn(py, syv[s]);
          const float d2 = add_rn(mul_rn(dx, dx), mul_rn(dy, dy));
          if (d2 < bd2v[s]) { bd2v[s] = d2; bidxv[s] = j; }  // strict <: lowest j
        }
      }
    }

    // 64-lane butterfly per sample (lowest-index tie-break == np.argmin)
    #pragma unroll
    for (int s = 0; s < 4; ++s) {
      #pragma unroll
      for (int m = 32; m >= 1; m >>= 1) {
        const float od2 = __shfl_xor(bd2v[s], m, 64);
        const int oidx = __shfl_xor(bidxv[s], m, 64);
        if (od2 < bd2v[s] || (od2 == bd2v[s] && oidx < bidxv[s])) {
          bd2v[s] = od2; bidxv[s] = oidx;
        }
      }
    }
    // stash partials in the not-yet-written node slots (consumed by Phase B)
    if (lane == 0) {
      #pragma unroll
      for (int s = 0; s < 4; ++s) {
        nodesL[c + wave * 4 + s] = make_float2(bd2v[s], __int_as_float(bidxv[s]));
      }
    }
    __syncthreads();

    // ---- Phase B: wave 0 runs the 64 sequential steps. Each lane pre-steers
    // its candidate node so the per-step chain is 2 readlanes + dist + select.
    if (tid < 64) {
      // this lane owns iteration c+lane: recompute ITS sample
      float sxx, syy;
      {
        const int i = c + lane;
        const float uu = u[i];
        if (uu < 0.1f) { sxx = gx; syy = gy; }
        else {
          sxx = mul_rn(r[2 * i], 200.0f);
          syy = mul_rn(r[2 * i + 1], 200.0f);
        }
      }

      const float2 part = nodesL[c + lane];
      float bd2 = part.x;
      const int bidx = __float_as_int(part.y);
      float bx, by;
      if (bidx == 0) { bx = n0x; by = n0y; }
      else { const float2 bp = nodesL[bidx - 1]; bx = bp.x; by = bp.y; }

      // pre-steer: candidate new node if this lane's argmin state is final
      float dirx = sub_rn(sxx, bx), diry = sub_rn(syy, by);
      float dist = __fsqrt_rn(add_rn(bd2, 1e-12f));
      float scl = (dist > 5.0f) ? __fdiv_rn(5.0f, dist) : 1.0f;
      float nx = add_rn(bx, mul_rn(dirx, scl));
      float ny = add_rn(by, mul_rn(diry, scl));

      for (int t = 0; t < NCHUNK; ++t) {
        const float px = bcastf(nx, t);   // lane t's steered node == node c+t+1
        const float py = bcastf(ny, t);
        if (lane == t) nodesL[c + t] = make_float2(nx, ny);
        if (lane > t) {  // pending samples absorb the new node
          const float dx = sub_rn(px, sxx);
          const float dy = sub_rn(py, syy);
          const float nd2 = add_rn(mul_rn(dx, dx), mul_rn(dy, dy));
          if (nd2 < bd2) {  // strict <: old (lower) index wins ties
            bd2 = nd2; bx = px; by = py;
            dirx = sub_rn(sxx, bx); diry = sub_rn(syy, by);
            dist = __fsqrt_rn(add_rn(bd2, 1e-12f));
            scl = (dist > 5.0f) ? __fdiv_rn(5.0f, dist) : 1.0f;
            nx = add_rn(bx, mul_rn(dirx, scl));
            ny = add_rn(by, mul_rn(diry, scl));
          }
        }
      }
    }
    __syncthreads();
  }

  // ---- write out nodes[0..8192] as float pairs
  if (tid == 0) { out[0] = n0x; out[1] = n0y; }
  for (int i = 1 + tid; i <= MAX_ITER; i += NTHREADS) {
    const float2 p = nodesL[i - 1];
    out[2 * i] = p.x;
    out[2 * i + 1] = p.y;
  }
}

extern "C" void kernel_launch(void* const* d_in, const int* in_sizes, int n_in,
                              void* d_out, int out_size, void* d_ws, size_t ws_size,
                              hipStream_t stream) {
  const float* state = (const float*)d_in[0];
  const float* goal  = (const float*)d_in[1];
  const float* u     = (const float*)d_in[2];
  const float* r     = (const float*)d_in[3];
  float* out = (float*)d_out;
  (void)in_sizes; (void)n_in; (void)out_size; (void)d_ws; (void)ws_size;
  rrt_kernel<<<1, NTHREADS, 0, stream>>>(state, goal, u, r, out);
}

// Round 5
// 1538.227 us; speedup vs baseline: 2.4200x; 2.0098x over previous
//
#include <hip/hip_runtime.h>

#define MAX_ITER 8192
#define NCHUNK   64
#define NCHUNKS  128          // MAX_ITER / NCHUNK
#define NTHREADS 1024
#define NBLOCKS  17           // block 0 = coordinator, 1..16 = scanners (4 samples each)
#define MAGIC    0x13572468u

typedef unsigned long long u64;

// IEEE fp32 ops, contraction off -> bitwise numpy match (verified rounds 2-3).
__device__ __forceinline__ float mul_rn(float a, float b) {
#pragma clang fp contract(off)
  return a * b;
}
__device__ __forceinline__ float add_rn(float a, float b) {
#pragma clang fp contract(off)
  return a + b;
}
__device__ __forceinline__ float sub_rn(float a, float b) {
#pragma clang fp contract(off)
  return a - b;
}
__device__ __forceinline__ float bcastf(float v, int lane) {
  return __int_as_float(__builtin_amdgcn_readlane(__float_as_int(v), lane));
}
__device__ __forceinline__ void st_agent(u64* p, u64 v) {
  __hip_atomic_store(p, v, __ATOMIC_RELAXED, __HIP_MEMORY_SCOPE_AGENT);
}
__device__ __forceinline__ u64 ld_agent(u64* p) {
  return __hip_atomic_load(p, __ATOMIC_RELAXED, __HIP_MEMORY_SCOPE_AGENT);
}
__device__ __forceinline__ u64 packf2(float x, float y) {
  return ((u64)__float_as_uint(y) << 32) | (u64)__float_as_uint(x);
}
// __hip_atomic_fence doesn't exist in this ROCm; use the amdgcn builtin.
__device__ __forceinline__ void fence_rel_agent() {
  __builtin_amdgcn_fence(__ATOMIC_RELEASE, "agent");
}
__device__ __forceinline__ void fence_acq_agent() {
  __builtin_amdgcn_fence(__ATOMIC_ACQUIRE, "agent");
}

__global__ __launch_bounds__(NTHREADS) void rrt_kernel(
    const float* __restrict__ state, const float* __restrict__ goal,
    const float* __restrict__ u, const float* __restrict__ r,
    float* __restrict__ out, unsigned* __restrict__ ws) {
  __shared__ float2 nodesL[MAX_ITER];   // nodesL[j-1] == node j (node 0 in regs)

  u64* outU = (u64*)out;                // node i lives at outU[i] (float2-packed)
  unsigned* cnt  = ws;                  // byte offset 0
  unsigned* flag = ws + 32;             // byte offset 128
  unsigned* ini  = ws + 64;             // byte offset 256
  u64* Mbuf = (u64*)(ws + 128);         // byte offset 512: 2 x 64 u64, dbl-buffered

  const int tid  = threadIdx.x;
  const int wave = tid >> 6;
  const int lane = tid & 63;
  const int blk  = blockIdx.x;

  const float n0x = state[0], n0y = state[1];
  const float gx = goal[0],  gy = goal[1];

  // ---- init control words (d_ws is re-poisoned 0xAA before every launch)
  if (blk == 0) {
    if (tid == 0) {
      __hip_atomic_store(cnt, 0u, __ATOMIC_RELAXED, __HIP_MEMORY_SCOPE_AGENT);
      __hip_atomic_store(flag, 0u, __ATOMIC_RELAXED, __HIP_MEMORY_SCOPE_AGENT);
      fence_rel_agent();
      __hip_atomic_store(ini, MAGIC, __ATOMIC_RELAXED, __HIP_MEMORY_SCOPE_AGENT);
      st_agent(&outU[0], packf2(n0x, n0y));   // node 0
    }
  } else if (tid == 0) {
    while (__hip_atomic_load(ini, __ATOMIC_RELAXED, __HIP_MEMORY_SCOPE_AGENT) != MAGIC)
      __builtin_amdgcn_s_sleep(2);
    fence_acq_agent();
  }
  __syncthreads();

  if (blk == 0) {
    // ================= coordinator =================
    for (int k = 0; k < NCHUNKS; ++k) {
      const int c = k * NCHUNK;

      // ---- fixup: wave w owns samples s=4w..4w+3; lanes cover the 64 newest nodes
      #pragma unroll
      for (int s4 = 0; s4 < 4; ++s4) {
        const int s = wave * 4 + s4;
        const int i = c + s;
        float sx, sy;
        {
          const float uu = u[i];
          if (uu < 0.1f) { sx = gx; sy = gy; }
          else { sx = mul_rn(r[2 * i], 200.0f); sy = mul_rn(r[2 * i + 1], 200.0f); }
        }
        float bd2; int bidx;
        if (k == 0) {            // only node 0 exists
          const float dx = sub_rn(n0x, sx), dy = sub_rn(n0y, sy);
          bd2 = add_rn(mul_rn(dx, dx), mul_rn(dy, dy));
          bidx = 0;
        } else {
          const int j = c - NCHUNK + 1 + lane;      // nodes (c-64, c]
          const float2 p = nodesL[j - 1];
          const float dx = sub_rn(p.x, sx), dy = sub_rn(p.y, sy);
          bd2 = add_rn(mul_rn(dx, dx), mul_rn(dy, dy));
          bidx = j;
          #pragma unroll
          for (int m = 32; m >= 1; m >>= 1) {
            const float od2 = __shfl_xor(bd2, m, 64);
            const int  oidx = __shfl_xor(bidx, m, 64);
            if (od2 < bd2 || (od2 == bd2 && oidx < bidx)) { bd2 = od2; bidx = oidx; }
          }
          if (lane == 0) {       // combine with scanners' main partial (lower idx)
            const u64 mv = ld_agent(&Mbuf[(k & 1) * 64 + s]);
            const float md2 = __uint_as_float((unsigned)(mv >> 32));
            const int  midx = (int)(unsigned)(mv & 0xffffffffu);
            if (!(bd2 < md2)) { bd2 = md2; bidx = midx; }   // main wins ties
          }
        }
        if (lane == 0) nodesL[c + s] = make_float2(bd2, __int_as_float(bidx));
      }
      __syncthreads();

      // ---- Phase B (wave 0): numerics verbatim from bit-exact round-3 kernel
      if (tid < 64) {
        float sxx, syy;
        {
          const int i = c + lane;
          const float uu = u[i];
          if (uu < 0.1f) { sxx = gx; syy = gy; }
          else { sxx = mul_rn(r[2 * i], 200.0f); syy = mul_rn(r[2 * i + 1], 200.0f); }
        }
        const float2 part = nodesL[c + lane];
        float bd2 = part.x;
        const int bidx0 = __float_as_int(part.y);
        float bx, by;
        if (bidx0 == 0) { bx = n0x; by = n0y; }
        else { const float2 bp = nodesL[bidx0 - 1]; bx = bp.x; by = bp.y; }

        float dirx = sub_rn(sxx, bx), diry = sub_rn(syy, by);
        float dist = __fsqrt_rn(add_rn(bd2, 1e-12f));
        float scl = (dist > 5.0f) ? __fdiv_rn(5.0f, dist) : 1.0f;
        float nx = add_rn(bx, mul_rn(dirx, scl));
        float ny = add_rn(by, mul_rn(diry, scl));

        for (int t = 0; t < NCHUNK; ++t) {
          const float px = bcastf(nx, t);
          const float py = bcastf(ny, t);
          if (lane == t) nodesL[c + t] = make_float2(nx, ny);
          if (lane > t) {
            const float dx = sub_rn(px, sxx);
            const float dy = sub_rn(py, syy);
            const float nd2 = add_rn(mul_rn(dx, dx), mul_rn(dy, dy));
            if (nd2 < bd2) {    // strict <: older (lower) index wins ties
              bd2 = nd2; bx = px; by = py;
              dirx = sub_rn(sxx, bx); diry = sub_rn(syy, by);
              dist = __fsqrt_rn(add_rn(bd2, 1e-12f));
              scl = (dist > 5.0f) ? __fdiv_rn(5.0f, dist) : 1.0f;
              nx = add_rn(bx, mul_rn(dirx, scl));
              ny = add_rn(by, mul_rn(diry, scl));
            }
          }
        }
        st_agent(&outU[c + lane + 1], packf2(nx, ny));   // publish node c+lane+1
      }

      // ---- grid barrier (publish N_k / receive M_{k+1}); none after last chunk
      if (k < NCHUNKS - 1) {
        __syncthreads();
        if (tid == 0) {
          fence_rel_agent();
          const unsigned old = __hip_atomic_fetch_add(cnt, 1u, __ATOMIC_RELAXED,
                                                      __HIP_MEMORY_SCOPE_AGENT);
          if (old == (unsigned)(NBLOCKS * (k + 1) - 1)) {
            __hip_atomic_store(flag, (unsigned)(k + 1), __ATOMIC_RELAXED,
                               __HIP_MEMORY_SCOPE_AGENT);
          } else {
            while (__hip_atomic_load(flag, __ATOMIC_RELAXED,
                                     __HIP_MEMORY_SCOPE_AGENT) < (unsigned)(k + 1))
              __builtin_amdgcn_s_sleep(1);
          }
          fence_acq_agent();
        }
        __syncthreads();
      }
    }
  } else {
    // ================= scanners (blocks 1..16) =================
    const int sg = (blk - 1) * 4;      // my 4 samples within each chunk
    for (int k = 0; k < NCHUNKS - 1; ++k) {   // produce M_{k+1} during iteration k
      const int c = k * NCHUNK;

      // pull the 64 newest nodes N_{k-1} into LDS
      if (k >= 1 && wave == 0) {
        const int j = c - NCHUNK + 1 + lane;     // nodes (c-64, c]
        const u64 nv = ld_agent(&outU[j]);
        float2 p;
        p.x = __uint_as_float((unsigned)(nv & 0xffffffffu));
        p.y = __uint_as_float((unsigned)(nv >> 32));
        nodesL[j - 1] = p;
      }
      __syncthreads();

      // chunk k+1's samples (4 of them), scanned over nodes [0..c]
      float sxv[4], syv[4], bd2v[4];
      int bidxv[4];
      #pragma unroll
      for (int s = 0; s < 4; ++s) {
        const int i = (k + 1) * NCHUNK + sg + s;
        const float uu = u[i];
        if (uu < 0.1f) { sxv[s] = gx; syv[s] = gy; }
        else { sxv[s] = mul_rn(r[2 * i], 200.0f); syv[s] = mul_rn(r[2 * i + 1], 200.0f); }
        bd2v[s] = 3.0e38f; bidxv[s] = 0;
      }
      if (tid == 0) {       // node 0 handled from registers
        #pragma unroll
        for (int s = 0; s < 4; ++s) {
          const float dx = sub_rn(n0x, sxv[s]), dy = sub_rn(n0y, syv[s]);
          bd2v[s] = add_rn(mul_rn(dx, dx), mul_rn(dy, dy));
          bidxv[s] = 0;
        }
      }
      for (int j = 1 + tid; j <= c; j += NTHREADS) {
        const float2 p = nodesL[j - 1];
        #pragma unroll
        for (int s = 0; s < 4; ++s) {
          const float dx = sub_rn(p.x, sxv[s]), dy = sub_rn(p.y, syv[s]);
          const float d2 = add_rn(mul_rn(dx, dx), mul_rn(dy, dy));
          if (d2 < bd2v[s]) { bd2v[s] = d2; bidxv[s] = j; }  // strict <: lowest j
        }
      }
      // in-wave butterflies; stash wave partials in this chunk's future node slots
      #pragma unroll
      for (int s = 0; s < 4; ++s) {
        float bd2 = bd2v[s]; int bidx = bidxv[s];
        #pragma unroll
        for (int m = 32; m >= 1; m >>= 1) {
          const float od2 = __shfl_xor(bd2, m, 64);
          const int  oidx = __shfl_xor(bidx, m, 64);
          if (od2 < bd2 || (od2 == bd2 && oidx < bidx)) { bd2 = od2; bidx = oidx; }
        }
        if (lane == 0) nodesL[c + s * 16 + wave] = make_float2(bd2, __int_as_float(bidx));
      }
      __syncthreads();
      if (wave == 0) {       // final 16-way reduce per sample; publish M
        const float2 stv = nodesL[c + lane];   // lane = s*16 + wavepartial
        float bd2 = stv.x; int bidx = __float_as_int(stv.y);
        #pragma unroll
        for (int m = 8; m >= 1; m >>= 1) {
          const float od2 = __shfl_xor(bd2, m, 64);
          const int  oidx = __shfl_xor(bidx, m, 64);
          if (od2 < bd2 || (od2 == bd2 && oidx < bidx)) { bd2 = od2; bidx = oidx; }
        }
        if ((lane & 15) == 0) {
          const int s = lane >> 4;
          st_agent(&Mbuf[((k + 1) & 1) * 64 + sg + s],
                   ((u64)__float_as_uint(bd2) << 32) | (u64)(unsigned)bidx);
        }
      }
      // ---- grid barrier
      __syncthreads();
      if (tid == 0) {
        fence_rel_agent();
        const unsigned old = __hip_atomic_fetch_add(cnt, 1u, __ATOMIC_RELAXED,
                                                    __HIP_MEMORY_SCOPE_AGENT);
        if (old == (unsigned)(NBLOCKS * (k + 1) - 1)) {
          __hip_atomic_store(flag, (unsigned)(k + 1), __ATOMIC_RELAXED,
                             __HIP_MEMORY_SCOPE_AGENT);
        } else {
          while (__hip_atomic_load(flag, __ATOMIC_RELAXED,
                                   __HIP_MEMORY_SCOPE_AGENT) < (unsigned)(k + 1))
            __builtin_amdgcn_s_sleep(1);
        }
        fence_acq_agent();
      }
      __syncthreads();
    }
  }
}

extern "C" void kernel_launch(void* const* d_in, const int* in_sizes, int n_in,
                              void* d_out, int out_size, void* d_ws, size_t ws_size,
                              hipStream_t stream) {
  const float* state = (const float*)d_in[0];
  const float* goal  = (const float*)d_in[1];
  const float* u     = (const float*)d_in[2];
  const float* r     = (const float*)d_in[3];
  float* out = (float*)d_out;
  unsigned* ws = (unsigned*)d_ws;
  (void)in_sizes; (void)n_in; (void)out_size; (void)ws_size;
  rrt_kernel<<<NBLOCKS, NTHREADS, 0, stream>>>(state, goal, u, r, out, ws);
}

// Round 6
// 1479.563 us; speedup vs baseline: 2.5160x; 1.0396x over previous
//
#include <hip/hip_runtime.h>

#define MAX_ITER 8192
#define NCHUNK   64
#define NCHUNKS  128          // MAX_ITER / NCHUNK
#define NTHREADS 1024
#define NBLOCKS  17           // block 0 = coordinator, 1..16 = scanners (4 samples each)
#define MAGIC    0x13572468u

typedef unsigned long long u64;

// IEEE fp32 ops, contraction off -> bitwise numpy match (verified rounds 2-5).
__device__ __forceinline__ float mul_rn(float a, float b) {
#pragma clang fp contract(off)
  return a * b;
}
__device__ __forceinline__ float add_rn(float a, float b) {
#pragma clang fp contract(off)
  return a + b;
}
__device__ __forceinline__ float sub_rn(float a, float b) {
#pragma clang fp contract(off)
  return a - b;
}
__device__ __forceinline__ float bcastf(float v, int lane) {
  return __int_as_float(__builtin_amdgcn_readlane(__float_as_int(v), lane));
}
__device__ __forceinline__ void st_agent(u64* p, u64 v) {
  __hip_atomic_store(p, v, __ATOMIC_RELAXED, __HIP_MEMORY_SCOPE_AGENT);
}
__device__ __forceinline__ u64 ld_agent(u64* p) {
  return __hip_atomic_load(p, __ATOMIC_RELAXED, __HIP_MEMORY_SCOPE_AGENT);
}
__device__ __forceinline__ void st_agent32(unsigned* p, unsigned v) {
  __hip_atomic_store(p, v, __ATOMIC_RELAXED, __HIP_MEMORY_SCOPE_AGENT);
}
__device__ __forceinline__ unsigned ld_agent32(unsigned* p) {
  return __hip_atomic_load(p, __ATOMIC_RELAXED, __HIP_MEMORY_SCOPE_AGENT);
}
__device__ __forceinline__ u64 packf2(float x, float y) {
  return ((u64)__float_as_uint(y) << 32) | (u64)__float_as_uint(x);
}
// Release ordering for sc1 (LLC-coherent) atomics: drain own stores, and act as
// a compiler barrier. No buffer_wbl2/inv needed — everything cross-visible is
// an agent-scope atomic performed at the LLC.
__device__ __forceinline__ void waitcnt_vm0() {
  asm volatile("s_waitcnt vmcnt(0)" ::: "memory");
}
__device__ __forceinline__ void compiler_fence() {
  asm volatile("" ::: "memory");
}

__global__ __launch_bounds__(NTHREADS) void rrt_kernel(
    const float* __restrict__ state, const float* __restrict__ goal,
    const float* __restrict__ u, const float* __restrict__ r,
    float* __restrict__ out, unsigned* __restrict__ ws) {
  __shared__ float2 nodesL[MAX_ITER];   // nodesL[j-1] == node j (node 0 in regs)

  u64* outU = (u64*)out;                // node i lives at outU[i] (float2-packed)
  unsigned* mcnt  = ws;                 // scanner completion counter (byte 0)
  unsigned* nflag = ws + 32;            // coordinator epoch (byte 128)
  unsigned* ini   = ws + 64;            // init guard (byte 256)
  u64* Mbuf = (u64*)(ws + 128);         // byte 512: 2 x 64 u64, double-buffered

  const int tid  = threadIdx.x;
  const int wave = tid >> 6;
  const int lane = tid & 63;
  const int blk  = blockIdx.x;

  const float n0x = state[0], n0y = state[1];
  const float gx = goal[0],  gy = goal[1];

  // ---- init control words (d_ws is re-poisoned 0xAA before every launch)
  if (blk == 0) {
    if (tid == 0) {
      st_agent32(mcnt, 0u);
      st_agent32(nflag, 0u);
      st_agent(&outU[0], packf2(n0x, n0y));   // node 0
      waitcnt_vm0();
      st_agent32(ini, MAGIC);
    }
  } else if (tid == 0) {
    while (ld_agent32(ini) != MAGIC) __builtin_amdgcn_s_sleep(2);
    compiler_fence();
  }
  __syncthreads();

  if (blk == 0) {
    // ================= coordinator =================
    for (int k = 0; k < NCHUNKS; ++k) {
      const int c = k * NCHUNK;

      // wait for all 16 scanner partials M_k (produced during their iter k-1)
      if (k >= 1 && tid == 0) {
        while (ld_agent32(mcnt) < (unsigned)(16 * k)) __builtin_amdgcn_s_sleep(1);
        compiler_fence();
      }
      __syncthreads();

      // ---- fixup: wave w owns samples 4w..4w+3; lanes cover the 64 newest
      // nodes (in LDS from the previous Phase B); combine with scanner M.
      const int sbase = wave * 4;
      u64 mv[4];
      if (k >= 1 && lane == 0) {
        #pragma unroll
        for (int s4 = 0; s4 < 4; ++s4)
          mv[s4] = ld_agent(&Mbuf[(k & 1) * 64 + sbase + s4]);  // 4 indep loads
      }
      #pragma unroll
      for (int s4 = 0; s4 < 4; ++s4) {
        const int s = sbase + s4;
        const int i = c + s;
        float sx, sy;
        {
          const float uu = u[i];
          if (uu < 0.1f) { sx = gx; sy = gy; }
          else { sx = mul_rn(r[2 * i], 200.0f); sy = mul_rn(r[2 * i + 1], 200.0f); }
        }
        float bd2; int bidx;
        if (k == 0) {            // only node 0 exists
          const float dx = sub_rn(n0x, sx), dy = sub_rn(n0y, sy);
          bd2 = add_rn(mul_rn(dx, dx), mul_rn(dy, dy));
          bidx = 0;
        } else {
          const int j = c - NCHUNK + 1 + lane;      // nodes (c-64, c]
          const float2 p = nodesL[j - 1];
          const float dx = sub_rn(p.x, sx), dy = sub_rn(p.y, sy);
          bd2 = add_rn(mul_rn(dx, dx), mul_rn(dy, dy));
          bidx = j;
          #pragma unroll
          for (int m = 32; m >= 1; m >>= 1) {
            const float od2 = __shfl_xor(bd2, m, 64);
            const int  oidx = __shfl_xor(bidx, m, 64);
            if (od2 < bd2 || (od2 == bd2 && oidx < bidx)) { bd2 = od2; bidx = oidx; }
          }
          if (lane == 0) {       // scanner M covers lower indices: wins ties
            const float md2 = __uint_as_float((unsigned)(mv[s4] >> 32));
            const int  midx = (int)(unsigned)(mv[s4] & 0xffffffffu);
            if (!(bd2 < md2)) { bd2 = md2; bidx = midx; }
          }
        }
        if (lane == 0) nodesL[c + s] = make_float2(bd2, __int_as_float(bidx));
      }
      __syncthreads();

      // ---- Phase B (wave 0): numerics verbatim from bit-exact round-3 kernel
      if (tid < 64) {
        float sxx, syy;
        {
          const int i = c + lane;
          const float uu = u[i];
          if (uu < 0.1f) { sxx = gx; syy = gy; }
          else { sxx = mul_rn(r[2 * i], 200.0f); syy = mul_rn(r[2 * i + 1], 200.0f); }
        }
        const float2 part = nodesL[c + lane];
        float bd2 = part.x;
        const int bidx0 = __float_as_int(part.y);
        float bx, by;
        if (bidx0 == 0) { bx = n0x; by = n0y; }
        else { const float2 bp = nodesL[bidx0 - 1]; bx = bp.x; by = bp.y; }

        float dirx = sub_rn(sxx, bx), diry = sub_rn(syy, by);
        float dist = __fsqrt_rn(add_rn(bd2, 1e-12f));
        float scl = (dist > 5.0f) ? __fdiv_rn(5.0f, dist) : 1.0f;
        float nx = add_rn(bx, mul_rn(dirx, scl));
        float ny = add_rn(by, mul_rn(diry, scl));

        for (int t = 0; t < NCHUNK; ++t) {
          const float px = bcastf(nx, t);
          const float py = bcastf(ny, t);
          if (lane == t) nodesL[c + t] = make_float2(nx, ny);
          if (lane > t) {
            const float dx = sub_rn(px, sxx);
            const float dy = sub_rn(py, syy);
            const float nd2 = add_rn(mul_rn(dx, dx), mul_rn(dy, dy));
            if (nd2 < bd2) {    // strict <: older (lower) index wins ties
              bd2 = nd2; bx = px; by = py;
              dirx = sub_rn(sxx, bx); diry = sub_rn(syy, by);
              dist = __fsqrt_rn(add_rn(bd2, 1e-12f));
              scl = (dist > 5.0f) ? __fdiv_rn(5.0f, dist) : 1.0f;
              nx = add_rn(bx, mul_rn(dirx, scl));
              ny = add_rn(by, mul_rn(diry, scl));
            }
          }
        }
        st_agent(&outU[c + lane + 1], packf2(nx, ny));   // publish node c+lane+1
        waitcnt_vm0();                                   // drain before epoch
        if (lane == 0 && k < NCHUNKS - 1) st_agent32(nflag, (unsigned)(k + 1));
      }
      __syncthreads();   // Phase B's nodesL writes -> next iter's fixup reads
    }
  } else {
    // ================= scanners (blocks 1..16) =================
    const int sg = (blk - 1) * 4;      // my 4 samples within each chunk
    for (int k = 0; k < NCHUNKS - 1; ++k) {   // produce M_{k+1} during iter k
      const int c = k * NCHUNK;

      if (k >= 1 && tid == 0) {        // need epoch k (nodes through 64k)
        while (ld_agent32(nflag) < (unsigned)k) __builtin_amdgcn_s_sleep(1);
        compiler_fence();
      }
      __syncthreads();

      // pull the 64 newest nodes into LDS
      if (k >= 1 && wave == 0) {
        const int j = c - NCHUNK + 1 + lane;     // nodes (c-64, c]
        const u64 nv = ld_agent(&outU[j]);
        float2 p;
        p.x = __uint_as_float((unsigned)(nv & 0xffffffffu));
        p.y = __uint_as_float((unsigned)(nv >> 32));
        nodesL[j - 1] = p;
      }
      __syncthreads();

      // chunk k+1's samples (4 of them), scanned over nodes [0..c]
      float sxv[4], syv[4], bd2v[4];
      int bidxv[4];
      #pragma unroll
      for (int s = 0; s < 4; ++s) {
        const int i = (k + 1) * NCHUNK + sg + s;
        const float uu = u[i];
        if (uu < 0.1f) { sxv[s] = gx; syv[s] = gy; }
        else { sxv[s] = mul_rn(r[2 * i], 200.0f); syv[s] = mul_rn(r[2 * i + 1], 200.0f); }
        bd2v[s] = 3.0e38f; bidxv[s] = 0;
      }
      if (tid == 0) {       // node 0 handled from registers
        #pragma unroll
        for (int s = 0; s < 4; ++s) {
          const float dx = sub_rn(n0x, sxv[s]), dy = sub_rn(n0y, syv[s]);
          bd2v[s] = add_rn(mul_rn(dx, dx), mul_rn(dy, dy));
          bidxv[s] = 0;
        }
      }
      for (int j = 1 + tid; j <= c; j += NTHREADS) {
        const float2 p = nodesL[j - 1];
        #pragma unroll
        for (int s = 0; s < 4; ++s) {
          const float dx = sub_rn(p.x, sxv[s]), dy = sub_rn(p.y, syv[s]);
          const float d2 = add_rn(mul_rn(dx, dx), mul_rn(dy, dy));
          if (d2 < bd2v[s]) { bd2v[s] = d2; bidxv[s] = j; }  // strict <: lowest j
        }
      }
      // in-wave butterflies; stash wave partials in future node slots
      #pragma unroll
      for (int s = 0; s < 4; ++s) {
        float bd2 = bd2v[s]; int bidx = bidxv[s];
        #pragma unroll
        for (int m = 32; m >= 1; m >>= 1) {
          const float od2 = __shfl_xor(bd2, m, 64);
          const int  oidx = __shfl_xor(bidx, m, 64);
          if (od2 < bd2 || (od2 == bd2 && oidx < bidx)) { bd2 = od2; bidx = oidx; }
        }
        if (lane == 0) nodesL[c + s * 16 + wave] = make_float2(bd2, __int_as_float(bidx));
      }
      __syncthreads();
      if (wave == 0) {       // final 16-way reduce per sample; publish M
        const float2 stv = nodesL[c + lane];   // lane = s*16 + wavepartial
        float bd2 = stv.x; int bidx = __float_as_int(stv.y);
        #pragma unroll
        for (int m = 8; m >= 1; m >>= 1) {
          const float od2 = __shfl_xor(bd2, m, 64);
          const int  oidx = __shfl_xor(bidx, m, 64);
          if (od2 < bd2 || (od2 == bd2 && oidx < bidx)) { bd2 = od2; bidx = oidx; }
        }
        if ((lane & 15) == 0) {
          const int s = lane >> 4;
          st_agent(&Mbuf[((k + 1) & 1) * 64 + sg + s],
                   ((u64)__float_as_uint(bd2) << 32) | (u64)(unsigned)bidx);
        }
        waitcnt_vm0();       // drain the 4 M stores (issued by lanes 0/16/32/48)
        if (lane == 0)
          __hip_atomic_fetch_add(mcnt, 1u, __ATOMIC_RELAXED, __HIP_MEMORY_SCOPE_AGENT);
      }
      // no trailing barrier: top-of-loop poll + syncthreads handle reuse;
      // waves 1..15 park at the next __syncthreads until wave 0 (tid 0) passes
      // the poll, so the stash slots can't be overwritten early.
    }
  }
}

extern "C" void kernel_launch(void* const* d_in, const int* in_sizes, int n_in,
                              void* d_out, int out_size, void* d_ws, size_t ws_size,
                              hipStream_t stream) {
  const float* state = (const float*)d_in[0];
  const float* goal  = (const float*)d_in[1];
  const float* u     = (const float*)d_in[2];
  const float* r     = (const float*)d_in[3];
  float* out = (float*)d_out;
  unsigned* ws = (unsigned*)d_ws;
  (void)in_sizes; (void)n_in; (void)out_size; (void)ws_size;
  rrt_kernel<<<NBLOCKS, NTHREADS, 0, stream>>>(state, goal, u, r, out, ws);
}

// Round 7
// 1288.678 us; speedup vs baseline: 2.8886x; 1.1481x over previous
//
#include <hip/hip_runtime.h>

#define MAX_ITER 8192
#define NCHUNK   64
#define NCHUNKS  128          // MAX_ITER / NCHUNK
#define NTHREADS 1024
#define NBLOCKS  17           // block 0 = coordinator (wave 0 only), 1..16 = scanners
#define MAGIC    0x13572468u

typedef unsigned long long u64;
#define KEY_MAX 0xffffffffffffffffull

// IEEE fp32 ops, contraction off -> bitwise numpy match (verified rounds 2-6).
__device__ __forceinline__ float mul_rn(float a, float b) {
#pragma clang fp contract(off)
  return a * b;
}
__device__ __forceinline__ float add_rn(float a, float b) {
#pragma clang fp contract(off)
  return a + b;
}
__device__ __forceinline__ float sub_rn(float a, float b) {
#pragma clang fp contract(off)
  return a - b;
}
__device__ __forceinline__ float bcastf(float v, int lane) {
  return __int_as_float(__builtin_amdgcn_readlane(__float_as_int(v), lane));
}
__device__ __forceinline__ void st_agent(u64* p, u64 v) {
  __hip_atomic_store(p, v, __ATOMIC_RELAXED, __HIP_MEMORY_SCOPE_AGENT);
}
__device__ __forceinline__ u64 ld_agent(u64* p) {
  return __hip_atomic_load(p, __ATOMIC_RELAXED, __HIP_MEMORY_SCOPE_AGENT);
}
__device__ __forceinline__ void st_agent32(unsigned* p, unsigned v) {
  __hip_atomic_store(p, v, __ATOMIC_RELAXED, __HIP_MEMORY_SCOPE_AGENT);
}
__device__ __forceinline__ unsigned ld_agent32(unsigned* p) {
  return __hip_atomic_load(p, __ATOMIC_RELAXED, __HIP_MEMORY_SCOPE_AGENT);
}
__device__ __forceinline__ u64 packf2(float x, float y) {
  return ((u64)__float_as_uint(y) << 32) | (u64)__float_as_uint(x);
}
__device__ __forceinline__ void waitcnt_vm0() {
  asm volatile("s_waitcnt vmcnt(0)" ::: "memory");
}
__device__ __forceinline__ void compiler_fence() {
  asm volatile("" ::: "memory");
}
// Exact (d2, idx) lexicographic key: d2 >= 0 so f32 bits are order-monotonic.
__device__ __forceinline__ u64 mkkey(float d2, int idx) {
  return ((u64)__float_as_uint(d2) << 32) | (u64)(unsigned)idx;
}

__global__ __launch_bounds__(NTHREADS) void rrt_kernel(
    const float* __restrict__ state, const float* __restrict__ goal,
    const float* __restrict__ u, const float* __restrict__ r,
    float* __restrict__ out, unsigned* __restrict__ ws) {
  // scanners: nodes 1..8064 (all a scan ever needs); 64512 B + 128 B < 64 KiB
  __shared__ float2 nodesL[8064];
  __shared__ u64 sharedK[16];

  u64* outU = (u64*)out;                // node i at outU[i] (float2-packed)
  unsigned* mcnt  = ws;                 // scanner completion counter (byte 0)
  unsigned* nflag = ws + 32;            // coordinator epoch (byte 128)
  unsigned* ini   = ws + 64;            // init guard (byte 256)
  u64* MbufK = (u64*)(ws + 128);        // byte 512:  2 x 64 keys (dbl-buffered)
  u64* MbufC = (u64*)(ws + 512);        // byte 2048: 2 x 64 packed coords

  const int tid  = threadIdx.x;
  const int wave = tid >> 6;
  const int lane = tid & 63;
  const int blk  = blockIdx.x;

  const float n0x = state[0], n0y = state[1];
  const float gx = goal[0],  gy = goal[1];

  // ---- init control words (d_ws re-poisoned 0xAA before every launch)
  if (blk == 0) {
    if (tid == 0) {
      st_agent32(mcnt, 0u);
      st_agent32(nflag, 0u);
      st_agent(&outU[0], packf2(n0x, n0y));   // node 0
      waitcnt_vm0();
      st_agent32(ini, MAGIC);
    }
  } else if (tid == 0) {
    while (ld_agent32(ini) != MAGIC) __builtin_amdgcn_s_sleep(2);
    compiler_fence();
  }
  __syncthreads();

  if (blk == 0) {
    // ================= coordinator: ONE wave, no LDS, no syncthreads =======
    if (tid >= 64) return;   // no barriers beyond this point in this block

    u64 carryK = KEY_MAX;            // carried argmin over (c-64, c]
    float cbx = 0.0f, cby = 0.0f;

    for (int k = 0; k < NCHUNKS; ++k) {
      const int c = k * NCHUNK;

      // my sample (iteration c+lane)
      float sx, sy;
      {
        const int i = c + lane;
        const float uu = u[i];
        if (uu < 0.1f) { sx = gx; sy = gy; }
        else { sx = mul_rn(r[2 * i], 200.0f); sy = mul_rn(r[2 * i + 1], 200.0f); }
      }

      // ---- assemble initial argmin state over [0..c]
      u64 key; float bx, by;
      if (k == 0) {
        const float dx = sub_rn(n0x, sx), dy = sub_rn(n0y, sy);
        key = mkkey(add_rn(mul_rn(dx, dx), mul_rn(dy, dy)), 0);
        bx = n0x; by = n0y;
      } else {
        // wait for all 16 scanner partials M_k (their iter k-1)
        while (ld_agent32(mcnt) < (unsigned)(16 * k)) __builtin_amdgcn_s_sleep(1);
        compiler_fence();
        const int par = k & 1;
        const u64 mk = ld_agent(&MbufK[par * 64 + lane]);   // coalesced
        const u64 mc = ld_agent(&MbufC[par * 64 + lane]);
        key = carryK; bx = cbx; by = cby;                   // covers (c-64, c]
        if (mk < key) {                                     // M covers [0..c-64]
          key = mk;
          bx = __uint_as_float((unsigned)(mc & 0xffffffffu));
          by = __uint_as_float((unsigned)(mc >> 32));
        }
      }

      // next-chunk sample + carried state (accumulates over (c, c+64])
      float nsx = 0.0f, nsy = 0.0f;
      u64 nk = KEY_MAX; float nbx = 0.0f, nby = 0.0f;
      if (k < NCHUNKS - 1) {
        const int i2 = c + NCHUNK + lane;
        const float uu = u[i2];
        if (uu < 0.1f) { nsx = gx; nsy = gy; }
        else { nsx = mul_rn(r[2 * i2], 200.0f); nsy = mul_rn(r[2 * i2 + 1], 200.0f); }
      }

      // pre-steer (round-3-verified math, d2 bits recovered exactly from key)
      float d2c = __uint_as_float((unsigned)(key >> 32));
      float dirx = sub_rn(sx, bx), diry = sub_rn(sy, by);
      float dist = __fsqrt_rn(add_rn(d2c, 1e-12f));
      float scl = (dist > 5.0f) ? __fdiv_rn(5.0f, dist) : 1.0f;
      float nx = add_rn(bx, mul_rn(dirx, scl));
      float ny = add_rn(by, mul_rn(diry, scl));

      // ---- 64 sequential steps
      for (int t = 0; t < NCHUNK; ++t) {
        const float px = bcastf(nx, t);   // node c+t+1
        const float py = bcastf(ny, t);
        if (lane > t) {                   // pending current-chunk samples
          const float dx = sub_rn(px, sx), dy = sub_rn(py, sy);
          const float nd2 = add_rn(mul_rn(dx, dx), mul_rn(dy, dy));
          const u64 nkey = mkkey(nd2, c + t + 1);
          if (nkey < key) {
            key = nkey; bx = px; by = py;
            dirx = sub_rn(sx, bx); diry = sub_rn(sy, by);
            dist = __fsqrt_rn(add_rn(nd2, 1e-12f));
            scl = (dist > 5.0f) ? __fdiv_rn(5.0f, dist) : 1.0f;
            nx = add_rn(bx, mul_rn(dirx, scl));
            ny = add_rn(by, mul_rn(diry, scl));
          }
        }
        if (k < NCHUNKS - 1) {            // next-chunk carried update (all lanes)
          const float dx = sub_rn(px, nsx), dy = sub_rn(py, nsy);
          const float nd2 = add_rn(mul_rn(dx, dx), mul_rn(dy, dy));
          const u64 nkey = mkkey(nd2, c + t + 1);
          if (nkey < nk) { nk = nkey; nbx = px; nby = py; }
        }
      }

      // publish the 64 new nodes + epoch
      st_agent(&outU[c + lane + 1], packf2(nx, ny));
      waitcnt_vm0();
      if (lane == 0 && k < NCHUNKS - 1) st_agent32(nflag, (unsigned)(k + 1));

      carryK = nk; cbx = nbx; cby = nby;
    }
  } else {
    // ================= scanners (blocks 1..16) =============================
    const int sg = (blk - 1) * 4;        // my 4 samples within each chunk
    const int s_loc = wave & 3;          // which of my 4 samples this wave works
    const int stripe = wave >> 2;        // 4-way node striping per sample

    for (int k = 0; k < NCHUNKS - 1; ++k) {   // iter k -> M_{k+1} over [0..64k]
      const int c = k * NCHUNK;

      // wave 0: poll epoch k, pull newest 64 nodes (disjoint LDS region)
      if (k >= 1 && wave == 0) {
        while (ld_agent32(nflag) < (unsigned)k) __builtin_amdgcn_s_sleep(1);
        compiler_fence();
        const int j = c - NCHUNK + 1 + lane;     // nodes (c-64, c]
        const u64 nv = ld_agent(&outU[j]);
        float2 p;
        p.x = __uint_as_float((unsigned)(nv & 0xffffffffu));
        p.y = __uint_as_float((unsigned)(nv >> 32));
        nodesL[j - 1] = p;
      }
      __syncthreads();

      // my sample: chunk k+1, slot sg+s_loc
      float sx, sy;
      {
        const int i = (k + 1) * NCHUNK + sg + s_loc;
        const float uu = u[i];
        if (uu < 0.1f) { sx = gx; sy = gy; }
        else { sx = mul_rn(r[2 * i], 200.0f); sy = mul_rn(r[2 * i + 1], 200.0f); }
      }

      u64 key = KEY_MAX;
      if (stripe == 0 && lane == 0) {          // node 0 (idx 0) once per sample
        const float dx = sub_rn(n0x, sx), dy = sub_rn(n0y, sy);
        key = mkkey(add_rn(mul_rn(dx, dx), mul_rn(dy, dy)), 0);
      }
      for (int j = 1 + stripe * NCHUNK + lane; j <= c; j += 256) {
        const float2 p = nodesL[j - 1];
        const float dx = sub_rn(p.x, sx), dy = sub_rn(p.y, sy);
        const u64 nkey = mkkey(add_rn(mul_rn(dx, dx), mul_rn(dy, dy)), j);
        if (nkey < key) key = nkey;
      }
      // wave butterfly (u64 keys -> exact ties)
      #pragma unroll
      for (int m = 32; m >= 1; m >>= 1) {
        const u64 ok = __shfl_xor(key, m, 64);
        if (ok < key) key = ok;
      }
      if (lane == 0) sharedK[wave] = key;
      __syncthreads();

      if (wave == 0) {
        u64 kk = (lane < 16) ? sharedK[lane] : KEY_MAX;
        {  // reduce across the 4 stripes of each sample (lanes s, s+4, s+8, s+12)
          u64 ok = __shfl_xor(kk, 4, 64); if (ok < kk) kk = ok;
          ok = __shfl_xor(kk, 8, 64);     if (ok < kk) kk = ok;
        }
        if (lane < 4) {
          const int s = sg + lane;
          const unsigned midx = (unsigned)(kk & 0xffffffffu);
          float mx, my;
          if (midx == 0) { mx = n0x; my = n0y; }
          else { const float2 p = nodesL[midx - 1]; mx = p.x; my = p.y; }
          const int par = (k + 1) & 1;
          st_agent(&MbufK[par * 64 + s], kk);
          st_agent(&MbufC[par * 64 + s], packf2(mx, my));
        }
        waitcnt_vm0();
        if (lane == 0)
          __hip_atomic_fetch_add(mcnt, 1u, __ATOMIC_RELAXED, __HIP_MEMORY_SCOPE_AGENT);
      }
      // no trailing barrier needed: next iter's LDS writes (pull region
      // [c,c+63], sharedK) are gated by the post-pull __syncthreads, and the
      // pull region is disjoint from anything read this iter.
    }
  }
}

extern "C" void kernel_launch(void* const* d_in, const int* in_sizes, int n_in,
                              void* d_out, int out_size, void* d_ws, size_t ws_size,
                              hipStream_t stream) {
  const float* state = (const float*)d_in[0];
  const float* goal  = (const float*)d_in[1];
  const float* u     = (const float*)d_in[2];
  const float* r     = (const float*)d_in[3];
  float* out = (float*)d_out;
  unsigned* ws = (unsigned*)d_ws;
  (void)in_sizes; (void)n_in; (void)out_size; (void)ws_size;
  rrt_kernel<<<NBLOCKS, NTHREADS, 0, stream>>>(state, goal, u, r, out, ws);
}

// Round 8
// 964.418 us; speedup vs baseline: 3.8599x; 1.3362x over previous
//
#include <hip/hip_runtime.h>

#define MAX_ITER 8192
#define NCHUNK   64
#define NCHUNKS  128          // MAX_ITER / NCHUNK
#define NSCAN    64           // scanner blocks, 1 sample each
#define NTHREADS 256
#define MAGIC    0x13572468u

typedef unsigned long long u64;
#define KEY_MAX 0xffffffffffffffffull

// IEEE fp32 ops, contraction off -> bitwise numpy match (verified rounds 2-7).
__device__ __forceinline__ float mul_rn(float a, float b) {
#pragma clang fp contract(off)
  return a * b;
}
__device__ __forceinline__ float add_rn(float a, float b) {
#pragma clang fp contract(off)
  return a + b;
}
__device__ __forceinline__ float sub_rn(float a, float b) {
#pragma clang fp contract(off)
  return a - b;
}
__device__ __forceinline__ float bcastf(float v, int lane) {
  return __int_as_float(__builtin_amdgcn_readlane(__float_as_int(v), lane));
}
__device__ __forceinline__ void st_agent(u64* p, u64 v) {
  __hip_atomic_store(p, v, __ATOMIC_RELAXED, __HIP_MEMORY_SCOPE_AGENT);
}
__device__ __forceinline__ u64 ld_agent(u64* p) {
  return __hip_atomic_load(p, __ATOMIC_RELAXED, __HIP_MEMORY_SCOPE_AGENT);
}
__device__ __forceinline__ void st_agent32(unsigned* p, unsigned v) {
  __hip_atomic_store(p, v, __ATOMIC_RELAXED, __HIP_MEMORY_SCOPE_AGENT);
}
__device__ __forceinline__ unsigned ld_agent32(unsigned* p) {
  return __hip_atomic_load(p, __ATOMIC_RELAXED, __HIP_MEMORY_SCOPE_AGENT);
}
__device__ __forceinline__ u64 packf2(float x, float y) {
  return ((u64)__float_as_uint(y) << 32) | (u64)__float_as_uint(x);
}
__device__ __forceinline__ void waitcnt_vm0() {
  asm volatile("s_waitcnt vmcnt(0)" ::: "memory");
}
__device__ __forceinline__ void compiler_fence() {
  asm volatile("" ::: "memory");
}
// Exact (d2, idx) lexicographic key (scanners only): d2 >= 0 -> bit-monotonic.
__device__ __forceinline__ u64 mkkey(float d2, int idx) {
  return ((u64)__float_as_uint(d2) << 32) | (u64)(unsigned)idx;
}

__global__ __launch_bounds__(NTHREADS) void rrt_kernel(
    const float* __restrict__ state, const float* __restrict__ goal,
    const float* __restrict__ u, const float* __restrict__ r,
    float* __restrict__ out, unsigned* __restrict__ ws) {
  // scanners hold nodes 1..8064 (max ever scanned); 64512 B < 64 KiB
  __shared__ __align__(16) float2 nodesL[8064];
  __shared__ u64 sharedK[4];

  u64* outU = (u64*)out;                // node i at outU[i] (float2-packed)
  unsigned* nflag = ws;                 // coordinator epoch       (byte 0)
  unsigned* ini   = ws + 32;            // init guard              (byte 128)
  u64* MbufK = (u64*)(ws + 64);         // 64 tagged keys          (byte 256)
  u64* MbufC = (u64*)(ws + 256);        // 64 packed coords        (byte 1024)

  const int tid  = threadIdx.x;
  const int wave = tid >> 6;
  const int lane = tid & 63;
  const int blk  = blockIdx.x;

  const float n0x = state[0], n0y = state[1];
  const float gx = goal[0],  gy = goal[1];

  if (blk == 0) {
    // ================= coordinator: one wave, no LDS, no barriers ==========
    if (tid == 0) {   // d_ws re-poisoned 0xAA each launch: poison tag = 85 != any first-read epoch
      st_agent32(nflag, 0u);
      st_agent(&outU[0], packf2(n0x, n0y));   // node 0
      waitcnt_vm0();
      st_agent32(ini, MAGIC);
    }
    if (tid >= 64) return;

    // current-chunk sample (chunk 0)
    float sx, sy;
    {
      const float uu = u[lane];
      if (uu < 0.1f) { sx = gx; sy = gy; }
      else { sx = mul_rn(r[2 * lane], 200.0f); sy = mul_rn(r[2 * lane + 1], 200.0f); }
    }
    float cbd2 = 3.0e38f, cbx = 0.0f, cby = 0.0f;   // carry over (c-64, c]

    for (int k = 0; k < NCHUNKS; ++k) {
      const int c = k * NCHUNK;
      const bool hasNext = (k < NCHUNKS - 1);

      // prefetch next-chunk sample before the poll (independent L2 loads)
      float nsx = 0.0f, nsy = 0.0f;
      if (hasNext) {
        const int i2 = c + NCHUNK + lane;
        const float uu = u[i2];
        if (uu < 0.1f) { nsx = gx; nsy = gy; }
        else { nsx = mul_rn(r[2 * i2], 200.0f); nsy = mul_rn(r[2 * i2 + 1], 200.0f); }
      }

      // ---- assemble argmin over [0..c]: scanner M [0..c-64] + carry (c-64,c]
      float bd2, bx, by;
      if (k == 0) {
        const float dx = sub_rn(n0x, sx), dy = sub_rn(n0y, sy);
        bd2 = add_rn(mul_rn(dx, dx), mul_rn(dy, dy));
        bx = n0x; by = n0y;
      } else {
        u64 kv;
        for (;;) {   // tag-in-key poll: one coalesced load, all 64 must match k
          kv = ld_agent(&MbufK[lane]);
          if (__all((int)(((unsigned)kv >> 13) & 0x7Fu) == k)) break;
          __builtin_amdgcn_s_sleep(1);
        }
        compiler_fence();
        const u64 cv = ld_agent(&MbufC[lane]);   // valid: C written before K
        const float md2 = __uint_as_float((unsigned)(kv >> 32));
        bd2 = cbd2; bx = cbx; by = cby;
        if (!(bd2 < md2)) {   // M's indices are all lower: M wins ties
          bd2 = md2;
          bx = __uint_as_float((unsigned)(cv & 0xffffffffu));
          by = __uint_as_float((unsigned)(cv >> 32));
        }
      }

      // pre-steer (round-3-verified math)
      float dirx = sub_rn(sx, bx), diry = sub_rn(sy, by);
      float dist = __fsqrt_rn(add_rn(bd2, 1e-12f));
      float scl = (dist > 5.0f) ? __fdiv_rn(5.0f, dist) : 1.0f;
      float nx = add_rn(bx, mul_rn(dirx, scl));
      float ny = add_rn(by, mul_rn(diry, scl));

      float nbd2 = 3.0e38f, nbx = 0.0f, nby = 0.0f;   // next carry

      // ---- 64 sequential steps; float-only (increasing idx => strict < ok)
      #pragma unroll 8
      for (int t = 0; t < NCHUNK; ++t) {
        const float px = bcastf(nx, t);   // node c+t+1
        const float py = bcastf(ny, t);
        if (lane > t) {
          const float dx = sub_rn(px, sx), dy = sub_rn(py, sy);
          const float nd2 = add_rn(mul_rn(dx, dx), mul_rn(dy, dy));
          if (nd2 < bd2) {               // rare: recompute steer
            bd2 = nd2; bx = px; by = py;
            dirx = sub_rn(sx, bx); diry = sub_rn(sy, by);
            dist = __fsqrt_rn(add_rn(nd2, 1e-12f));
            scl = (dist > 5.0f) ? __fdiv_rn(5.0f, dist) : 1.0f;
            nx = add_rn(bx, mul_rn(dirx, scl));
            ny = add_rn(by, mul_rn(diry, scl));
          }
        }
        {  // carried next-chunk update (independent; hides in readlane stalls)
          const float dx = sub_rn(px, nsx), dy = sub_rn(py, nsy);
          const float nd2 = add_rn(mul_rn(dx, dx), mul_rn(dy, dy));
          if (nd2 < nbd2) { nbd2 = nd2; nbx = px; nby = py; }
        }
      }

      st_agent(&outU[c + lane + 1], packf2(nx, ny));
      waitcnt_vm0();                     // wave-level drain of all 64 stores
      if (lane == 0 && hasNext) st_agent32(nflag, (unsigned)(k + 1));

      cbd2 = nbd2; cbx = nbx; cby = nby;
      sx = nsx; sy = nsy;
    }
  } else {
    // ================= scanners: blocks 1..64, one sample each =============
    const int b = blk - 1;
    if (tid == 0) {
      while (ld_agent32(ini) != MAGIC) __builtin_amdgcn_s_sleep(2);
      compiler_fence();
    }
    __syncthreads();

    for (int k = 0; k < NCHUNKS - 1; ++k) {   // iter k -> M_{k+1} over [0..64k]
      const int c = k * NCHUNK;

      if (k >= 1 && wave == 0) {   // poll epoch k; pull newest 64 nodes
        while (ld_agent32(nflag) < (unsigned)k) __builtin_amdgcn_s_sleep(1);
        compiler_fence();
        const int j = c - NCHUNK + 1 + lane;   // nodes (c-64, c]
        const u64 nv = ld_agent(&outU[j]);
        float2 p;
        p.x = __uint_as_float((unsigned)(nv & 0xffffffffu));
        p.y = __uint_as_float((unsigned)(nv >> 32));
        nodesL[j - 1] = p;
      }
      __syncthreads();

      // my sample: chunk k+1, slot b
      float sx, sy;
      {
        const int i = (k + 1) * NCHUNK + b;
        const float uu = u[i];
        if (uu < 0.1f) { sx = gx; sy = gy; }
        else { sx = mul_rn(r[2 * i], 200.0f); sy = mul_rn(r[2 * i + 1], 200.0f); }
      }

      u64 key = KEY_MAX;
      if (tid == 0) {   // node 0
        const float dx = sub_rn(n0x, sx), dy = sub_rn(n0y, sy);
        key = mkkey(add_rn(mul_rn(dx, dx), mul_rn(dy, dy)), 0);
      }
      // 256 lanes stride node pairs; float4 = nodes (j, j+1), j odd
      for (int j = 1 + 2 * tid; j < c; j += 2 * NTHREADS) {
        const float4 p = *(const float4*)&nodesL[j - 1];
        const float dxa = sub_rn(p.x, sx), dya = sub_rn(p.y, sy);
        const u64 ka = mkkey(add_rn(mul_rn(dxa, dxa), mul_rn(dya, dya)), j);
        const float dxb = sub_rn(p.z, sx), dyb = sub_rn(p.w, sy);
        const u64 kb = mkkey(add_rn(mul_rn(dxb, dxb), mul_rn(dyb, dyb)), j + 1);
        if (ka < key) key = ka;     // lower idx first: exact argmin ties
        if (kb < key) key = kb;
      }
      #pragma unroll
      for (int m = 32; m >= 1; m >>= 1) {
        const u64 ok = __shfl_xor(key, m, 64);
        if (ok < key) key = ok;
      }
      if (lane == 0) sharedK[wave] = key;
      __syncthreads();

      if (wave == 0) {
        u64 kk = (lane < 4) ? sharedK[lane] : KEY_MAX;
        u64 ok = __shfl_xor(kk, 1, 64); if (ok < kk) kk = ok;
        ok = __shfl_xor(kk, 2, 64);     if (ok < kk) kk = ok;
        if (lane == 0) {
          const unsigned midx = (unsigned)(kk & 0x1FFFu);   // idx < 8192
          float mx, my;
          if (midx == 0) { mx = n0x; my = n0y; }
          else { const float2 p = nodesL[midx - 1]; mx = p.x; my = p.y; }
          st_agent(&MbufC[b], packf2(mx, my));
          waitcnt_vm0();                                    // C lands before K
          st_agent(&MbufK[b], kk | ((u64)(unsigned)(k + 1) << 13));  // tag
        }
      }
      // next iter's LDS writes (nodes (c, c+64]) are disjoint from this iter's
      // reads and gated by the top-of-loop __syncthreads.
    }
  }
}

extern "C" void kernel_launch(void* const* d_in, const int* in_sizes, int n_in,
                              void* d_out, int out_size, void* d_ws, size_t ws_size,
                              hipStream_t stream) {
  const float* state = (const float*)d_in[0];
  const float* goal  = (const float*)d_in[1];
  const float* u     = (const float*)d_in[2];
  const float* r     = (const float*)d_in[3];
  float* out = (float*)d_out;
  unsigned* ws = (unsigned*)d_ws;
  (void)in_sizes; (void)n_in; (void)out_size; (void)ws_size;
  rrt_kernel<<<NSCAN + 1, NTHREADS, 0, stream>>>(state, goal, u, r, out, ws);
}